// Round 1
// baseline (358.811 us; speedup 1.0000x reference)
//
#include <hip/hip_runtime.h>

// CTC loss (keras ctc_batch_cost semantics): B=512, T=512, C=128, L=64.
// One wave (64 lanes) per batch element; lane l owns alpha states 2l, 2l+1;
// lane 63 additionally owns state 128. Cross-state deps via __shfl_up only.

constexpr int B = 512, T = 512, C = 128, L = 64;
constexpr int BLANK = C - 1;      // 127
constexpr float NEG = -1e30f;
constexpr float EPS = 1e-7f;

__device__ __forceinline__ float lae2(float x, float y) {
    // logaddexp(x, y)
    float m = fmaxf(x, y);
    float d = fminf(x, y) - m;          // <= 0 (0 when tie, incl. NEG/NEG)
    return m + __logf(1.0f + __expf(d));
}

__device__ __forceinline__ float lae3(float x, float y, float z) {
    // logaddexp(x, y, z)
    float m = fmaxf(fmaxf(x, y), z);
    float e = __expf(x - m) + __expf(y - m) + __expf(z - m);  // >= 1
    return m + __logf(e);
}

__global__ __launch_bounds__(64)
void ctc_kernel(const int* __restrict__ y_true,
                const float* __restrict__ y_pred,
                float* __restrict__ out) {
    const int b = blockIdx.x;
    const int l = threadIdx.x;          // lane 0..63

    const float* __restrict__ pb = y_pred + (size_t)b * T * C;

    // Label owned by this lane (state 2l+1), and skip-transition predicate.
    const int lab = y_true[b * L + l];
    const int lab_prev = __shfl_up(lab, 1);
    const bool allow1 = (l >= 1) && (lab != lab_prev);

    // ---- t = 0 init: only states 0 and 1 reachable ----
    float a0, a1, a2;
    {
        float pbl = pb[BLANK];
        float pla = pb[lab];
        a0 = (l == 0) ? __logf(pbl + EPS) : NEG;   // alpha[0]
        a1 = (l == 0) ? __logf(pla + EPS) : NEG;   // alpha[1]
        a2 = NEG;                                  // alpha[128] (lane 63)
    }

    // Prefetch t = 1 row values.
    float nb = pb[C + BLANK];
    float nl = pb[C + lab];

    for (int t = 1; t < T; ++t) {
        const float cb = nb;
        const float cl = nl;
        if (t + 1 < T) {                 // wave-uniform branch
            nb = pb[(t + 1) * C + BLANK];
            nl = pb[(t + 1) * C + lab];
        }
        const float lpb = __logf(cb + EPS);   // log p(blank)
        const float lpl = __logf(cl + EPS);   // log p(lab[l])

        // alpha[2l-1] from previous lane's a1.
        float p0 = __shfl_up(a1, 1);
        if (l == 0) p0 = NEG;

        // Even state 2l (blank): no skip ever allowed.
        const float na0 = lae2(a0, p0) + lpb;
        // Odd state 2l+1 (label): self, 2l, and skip from 2l-1 if allowed.
        const float na1 = lae3(a1, a0, allow1 ? p0 : NEG) + lpl;
        // State 128 (blank, lane 63): self + alpha[127] (old a1 of lane 63).
        const float na2 = lae2(a2, a1) + lpb;

        a0 = na0; a1 = na1; a2 = na2;
    }

    // loss = -logaddexp(alpha[S-1], alpha[S-2]) = -lae2(a2, a1@lane63)
    if (l == 63) {
        out[b] = -lae2(a2, a1);
    }
}

extern "C" void kernel_launch(void* const* d_in, const int* in_sizes, int n_in,
                              void* d_out, int out_size, void* d_ws, size_t ws_size,
                              hipStream_t stream) {
    const int*   y_true = (const int*)d_in[0];
    const float* y_pred = (const float*)d_in[1];
    float*       out    = (float*)d_out;
    ctc_kernel<<<dim3(B), dim3(64), 0, stream>>>(y_true, y_pred, out);
}

// Round 2
// 305.750 us; speedup vs baseline: 1.1735x; 1.1735x over previous
//
#include <hip/hip_runtime.h>

// CTC loss (keras ctc_batch_cost semantics): B=512, T=512, C=128, L=64.
// One wave (64 lanes) per batch element; lane l owns alpha states 2l, 2l+1;
// lane 63 additionally owns state 128. Cross-state deps via __shfl_up only.
// Deep (D=16) register prefetch pipeline to hide ~900-cycle HBM latency:
// at steady state 2*D loads are in flight per wave.

constexpr int B = 512, T = 512, C = 128, L = 64;
constexpr int BLANK = C - 1;      // 127
constexpr float NEG = -1e30f;
constexpr float EPS = 1e-7f;
constexpr int D = 16;             // prefetch depth (rows ahead)

__device__ __forceinline__ float lae2(float x, float y) {
    float m = fmaxf(x, y);
    float d = fminf(x, y) - m;          // <= 0
    return m + __logf(1.0f + __expf(d));
}

__device__ __forceinline__ float lae3(float x, float y, float z) {
    float m = fmaxf(fmaxf(x, y), z);
    float e = __expf(x - m) + __expf(y - m) + __expf(z - m);  // >= 1
    return m + __logf(e);
}

__global__ __launch_bounds__(64)
void ctc_kernel(const int* __restrict__ y_true,
                const float* __restrict__ y_pred,
                float* __restrict__ out) {
    const int b = blockIdx.x;
    const int l = threadIdx.x;          // lane 0..63

    const float* __restrict__ pb = y_pred + (size_t)b * T * C;

    const int lab = y_true[b * L + l];
    const int lab_prev = __shfl_up(lab, 1);
    const bool allow1 = (l >= 1) && (lab != lab_prev);

    // ---- t = 0 init: only states 0 and 1 reachable ----
    float a0, a1, a2;
    {
        float pbl = pb[BLANK];
        float pla = pb[lab];
        a0 = (l == 0) ? __logf(pbl + EPS) : NEG;   // alpha[0]
        a1 = (l == 0) ? __logf(pla + EPS) : NEG;   // alpha[1]
        a2 = NEG;                                  // alpha[128]
    }

    // ---- preload rows 1..D into the pipeline ----
    float nb[D], nl[D];
#pragma unroll
    for (int j = 0; j < D; ++j) {
        int r = 1 + j; if (r > T - 1) r = T - 1;
        nb[j] = pb[r * C + BLANK];
        nl[j] = pb[r * C + lab];
    }

    auto step = [&](int t, bool prefetch, int j) {
        const float cb = nb[j];
        const float cl = nl[j];
        if (prefetch) {
            int r = t + D; if (r > T - 1) r = T - 1;   // clamped re-read, harmless
            nb[j] = pb[r * C + BLANK];
            nl[j] = pb[r * C + lab];
        }
        const float lpb = __logf(cb + EPS);
        const float lpl = __logf(cl + EPS);

        float p0 = __shfl_up(a1, 1);           // alpha[2l-1]
        if (l == 0) p0 = NEG;

        const float na0 = lae2(a0, p0) + lpb;                       // state 2l
        const float na1 = lae3(a1, a0, allow1 ? p0 : NEG) + lpl;    // state 2l+1
        const float na2 = lae2(a2, a1) + lpb;                       // state 128

        a0 = na0; a1 = na1; a2 = na2;
    };

    // ---- main: 31 full chunks of D, t = 1..496 ----
    constexpr int FULL = (T - 1) / D;          // 31
    constexpr int TAIL = (T - 1) - FULL * D;   // 15
    int t = 1;
    for (int c = 0; c < FULL; ++c, t += D) {
#pragma unroll
        for (int j = 0; j < D; ++j) step(t + j, true, j);
    }
    // ---- tail: consume remaining prefetched slots, t = 497..511 ----
#pragma unroll
    for (int j = 0; j < TAIL; ++j) step(t + j, false, j);

    if (l == 63) {
        out[b] = -lae2(a2, a1);   // -logaddexp(alpha[128], alpha[127])
    }
}

extern "C" void kernel_launch(void* const* d_in, const int* in_sizes, int n_in,
                              void* d_out, int out_size, void* d_ws, size_t ws_size,
                              hipStream_t stream) {
    const int*   y_true = (const int*)d_in[0];
    const float* y_pred = (const float*)d_in[1];
    float*       out    = (float*)d_out;
    ctc_kernel<<<dim3(B), dim3(64), 0, stream>>>(y_true, y_pred, out);
}

// Round 4
// 218.919 us; speedup vs baseline: 1.6390x; 1.3966x over previous
//
#include <hip/hip_runtime.h>
#include <hip/hip_bf16.h>

// CTC loss, two-phase:
//   Phase 1 (gather_kernel, fully parallel): G[b][r][t] = p[b][t][ext_r] + EPS
//     as bf16, transposed so phase 2 reads each row contiguously over t.
//     r in [0,64): labels; r==64: blank.
//   Phase 2 (scan_kernel, 1 wave per batch): alpha recursion in LINEAR domain
//     (no transcendentals on the chain), DPP wave_shr for neighbor exchange,
//     wave-max renormalization every 8 steps with log2 scale accumulation.

constexpr int B = 512, T = 512, C = 128, L = 64;
constexpr int BLANK = C - 1;     // 127
constexpr int GR = L + 1;        // 65 gathered rows
constexpr float EPS = 1e-7f;
constexpr float NEG = -1e30f;
constexpr float LN2 = 0.69314718055994530942f;

// ---------------------------------------------------------------------------
// Phase 1: gather. Block = (b, 64-t tile), 256 threads. LDS-stage the 64x128
// prob tile (row pad +1 -> conflict-free column gathers), emit bf16 rows.
// ---------------------------------------------------------------------------
__global__ __launch_bounds__(256)
void gather_kernel(const int* __restrict__ y_true,
                   const float* __restrict__ y_pred,
                   __hip_bfloat16* __restrict__ G) {
    __shared__ float sp[64 * 129];   // 64 t-rows x 128 classes, +1 pad
    __shared__ int slab[GR];
    const int b   = blockIdx.x >> 3;
    const int t0  = (blockIdx.x & 7) * 64;
    const int tid = threadIdx.x;

    if (tid < GR) slab[tid] = (tid < L) ? y_true[b * L + tid] : BLANK;

    const float4* src4 = (const float4*)(y_pred + ((size_t)b * T + t0) * C);
#pragma unroll
    for (int i = 0; i < 8; ++i) {            // 2048 float4 / 256 threads
        const int idx = i * 256 + tid;
        const float4 v = src4[idx];
        const int r = (idx * 4) >> 7;        // t-row within tile
        const int c = (idx * 4) & 127;       // class column
        float* d = &sp[r * 129 + c];
        d[0] = v.x; d[1] = v.y; d[2] = v.z; d[3] = v.w;
    }
    __syncthreads();

    const int t_in = tid & 63;
    // bank = (t_in*129 + lab) % 32 = (t_in + lab) % 32 -> 2-way max (free)
    for (int r = (tid >> 6); r < GR; r += 4) {
        const float v = sp[t_in * 129 + slab[r]] + EPS;
        G[((size_t)b * GR + r) * T + t0 + t_in] = __float2bfloat16(v);
    }
}

// ---------------------------------------------------------------------------
// Phase 2: linear-domain scan, one wave per b.
// ---------------------------------------------------------------------------
__device__ __forceinline__ float dpp_wave_shr1(float x, float oldv) {
    // lane i <- lane i-1; lane 0 keeps oldv (bound_ctrl=false)
    return __int_as_float(__builtin_amdgcn_update_dpp(
        __float_as_int(oldv), __float_as_int(x), 0x138, 0xF, 0xF, false));
}
template <int CTRL>
__device__ __forceinline__ float dpp_max_step(float m) {
    float t = __int_as_float(__builtin_amdgcn_update_dpp(
        __float_as_int(m), __float_as_int(m), CTRL, 0xF, 0xF, false));
    return fmaxf(m, t);
}
__device__ __forceinline__ void unpack8(uint4 u, float* f) {
    f[0] = __uint_as_float(u.x << 16); f[1] = __uint_as_float(u.x & 0xFFFF0000u);
    f[2] = __uint_as_float(u.y << 16); f[3] = __uint_as_float(u.y & 0xFFFF0000u);
    f[4] = __uint_as_float(u.z << 16); f[5] = __uint_as_float(u.z & 0xFFFF0000u);
    f[6] = __uint_as_float(u.w << 16); f[7] = __uint_as_float(u.w & 0xFFFF0000u);
}

__global__ __launch_bounds__(64, 1)   // 1 wave/EU target: relax VGPR budget
void scan_kernel(const int* __restrict__ y_true,
                 const __hip_bfloat16* __restrict__ G,
                 float* __restrict__ out) {
    const int b = blockIdx.x;
    const int l = threadIdx.x;

    const int lab = y_true[b * L + l];
    const int lab_prev = __shfl_up(lab, 1);
    const bool allow1 = (l >= 1) && (lab != lab_prev);

    const uint4* lrow = (const uint4*)(G + ((size_t)b * GR + l) * T);  // own row
    const uint4* brow = (const uint4*)(G + ((size_t)b * GR + L) * T);  // blank (uniform)

    constexpr int NCH = 8;               // chunks (8 steps each) in flight
    uint4 pl[NCH], pk[NCH];
#pragma unroll
    for (int c = 0; c < NCH; ++c) { pl[c] = lrow[c]; pk[c] = brow[c]; }

    // Virtual pre-state: step t=0 of the uniform loop produces the true init.
    float a0 = (l == 0) ? 1.0f : 0.0f;   // alpha[2l]
    float a1 = 0.0f;                     // alpha[2l+1]
    float a2 = 0.0f;                     // alpha[128] (real on lane 63)
    float Csum = 0.0f;                   // accumulated log2 scale

#pragma unroll 8
    for (int c = 0; c < 64; ++c) {
        const int slot = c & 7;
        const uint4 ul = pl[slot];
        const uint4 ub = pk[slot];
        int nc = c + NCH; if (nc > 63) nc = 63;   // clamped redundant reload
        pl[slot] = lrow[nc];
        pk[slot] = brow[nc];

        float fl[8], fb[8];
        unpack8(ul, fl);
        unpack8(ub, fb);

#pragma unroll
        for (int j = 0; j < 8; ++j) {
            const float p0  = dpp_wave_shr1(a1, 0.0f);    // alpha[2l-1]
            const float na0 = (a0 + p0) * fb[j];
            const float na1 = (a1 + a0 + (allow1 ? p0 : 0.0f)) * fl[j];
            const float na2 = (a2 + a1) * fb[j];
            a0 = na0; a1 = na1; a2 = na2;
        }

        // Renormalize by wave-max every 8 steps (keeps values in f32 range).
        float m = fmaxf(a0, a1);
        m = dpp_max_step<0x111>(m);      // row_shr:1
        m = dpp_max_step<0x112>(m);      // row_shr:2
        m = dpp_max_step<0x114>(m);      // row_shr:4
        m = dpp_max_step<0x118>(m);      // row_shr:8
        m = dpp_max_step<0x142>(m);      // row_bcast:15
        m = dpp_max_step<0x143>(m);      // row_bcast:31 -> lane 63 has wave max
        const float M = __int_as_float(
            __builtin_amdgcn_readlane(__float_as_int(m), 63));
        const float r = __builtin_amdgcn_rcpf(M);
        Csum += __log2f(M);
        a0 *= r; a1 *= r; a2 *= r;
    }

    if (l == 63) {
        out[b] = -(Csum + __log2f(a2 + a1)) * LN2;
    }
}

// ---------------------------------------------------------------------------
// Fallback (R2 kernel, known-correct) if workspace is too small for G.
// ---------------------------------------------------------------------------
__device__ __forceinline__ float lae2(float x, float y) {
    float m = fmaxf(x, y);
    float d = fminf(x, y) - m;
    return m + __logf(1.0f + __expf(d));
}
__device__ __forceinline__ float lae3(float x, float y, float z) {
    float m = fmaxf(fmaxf(x, y), z);
    float e = __expf(x - m) + __expf(y - m) + __expf(z - m);
    return m + __logf(e);
}
__global__ __launch_bounds__(64)
void ctc_fallback(const int* __restrict__ y_true,
                  const float* __restrict__ y_pred,
                  float* __restrict__ out) {
    const int b = blockIdx.x;
    const int l = threadIdx.x;
    const float* __restrict__ pb = y_pred + (size_t)b * T * C;
    const int lab = y_true[b * L + l];
    const int lab_prev = __shfl_up(lab, 1);
    const bool allow1 = (l >= 1) && (lab != lab_prev);
    float a0, a1, a2;
    {
        float pbl = pb[BLANK];
        float pla = pb[lab];
        a0 = (l == 0) ? __logf(pbl + EPS) : NEG;
        a1 = (l == 0) ? __logf(pla + EPS) : NEG;
        a2 = NEG;
    }
    for (int t = 1; t < T; ++t) {
        const float lpb = __logf(pb[t * C + BLANK] + EPS);
        const float lpl = __logf(pb[t * C + lab] + EPS);
        float p0 = __shfl_up(a1, 1);
        if (l == 0) p0 = NEG;
        const float na0 = lae2(a0, p0) + lpb;
        const float na1 = lae3(a1, a0, allow1 ? p0 : NEG) + lpl;
        const float na2 = lae2(a2, a1) + lpb;
        a0 = na0; a1 = na1; a2 = na2;
    }
    if (l == 63) out[b] = -lae2(a2, a1);
}

extern "C" void kernel_launch(void* const* d_in, const int* in_sizes, int n_in,
                              void* d_out, int out_size, void* d_ws, size_t ws_size,
                              hipStream_t stream) {
    const int*   y_true = (const int*)d_in[0];
    const float* y_pred = (const float*)d_in[1];
    float*       out    = (float*)d_out;

    const size_t need = (size_t)B * GR * T * sizeof(__hip_bfloat16);  // ~34 MB
    if (ws_size >= need) {
        __hip_bfloat16* G = (__hip_bfloat16*)d_ws;
        gather_kernel<<<dim3(B * (T / 64)), dim3(256), 0, stream>>>(y_true, y_pred, G);
        scan_kernel<<<dim3(B), dim3(64), 0, stream>>>(y_true, G, out);
    } else {
        ctc_fallback<<<dim3(B), dim3(64), 0, stream>>>(y_true, y_pred, out);
    }
}

// Round 5
// 213.934 us; speedup vs baseline: 1.6772x; 1.0233x over previous
//
#include <hip/hip_runtime.h>
#include <hip/hip_bf16.h>

// CTC loss, two-phase:
//   Phase 1 (gather): G2[b][chunk][r] = uint4 packing 8 bf16 of
//     p[b][chunk*8+j][ext_r]+EPS  (r<64: label r, r==64: blank). Chunk-
//     interleaved so phase 2's per-chunk wave load is 1KB fully coalesced.
//   Phase 2 (scan): one wave per b, alpha recursion in LINEAR f64 domain
//     (range 1e+-308 swallows the inter-state spread that broke f32 in R4),
//     DPP wave_shr for the neighbor term, exact power-of-2 renorm every 32
//     steps via integer exponent max-reduce. Ping-pong register banks keep
//     32-step load->use distance; compact 8x loop body (I$-friendly).

typedef unsigned int u32;
typedef unsigned long long u64;

constexpr int B = 512, T = 512, C = 128, L = 64;
constexpr int BLANK = C - 1;     // 127
constexpr int GR = L + 1;        // 65 gathered rows
constexpr int NCHUNK = T / 8;    // 64 chunks of 8 timesteps
constexpr float EPS = 1e-7f;
constexpr float NEG = -1e30f;
constexpr float LN2 = 0.69314718055994530942f;

// ---------------------------------------------------------------------------
// Phase 1: gather + transpose + bf16 pack. Block = (b, 64-t tile), 256 thr.
// ---------------------------------------------------------------------------
__global__ __launch_bounds__(256)
void gather_kernel(const int* __restrict__ y_true,
                   const float* __restrict__ y_pred,
                   uint4* __restrict__ G2) {
    __shared__ float sp[64 * 128];   // 64 t-rows x 128 classes (32 KB)
    __shared__ int slab[GR];
    const int b   = blockIdx.x >> 3;
    const int t0  = (blockIdx.x & 7) * 64;
    const int tid = threadIdx.x;

    if (tid < GR) slab[tid] = (tid < L) ? y_true[b * L + tid] : BLANK;

    const float4* __restrict__ src4 =
        (const float4*)(y_pred + ((size_t)b * T + t0) * C);
    float4* sp4 = (float4*)sp;
#pragma unroll
    for (int i = 0; i < 8; ++i) sp4[i * 256 + tid] = src4[i * 256 + tid];
    __syncthreads();

    // 8 chunks x 65 rows = 520 packed uint4 outputs; r fastest -> coalesced.
#pragma unroll
    for (int it = 0; it < 3; ++it) {
        const int item = it * 256 + tid;
        if (item < 8 * GR) {
            const int chunk = item / GR;
            const int r     = item - chunk * GR;
            const int lab   = slab[r];
            u32 w[4];
#pragma unroll
            for (int q = 0; q < 4; ++q) {
                const float v0 = sp[(chunk * 8 + 2 * q)     * 128 + lab] + EPS;
                const float v1 = sp[(chunk * 8 + 2 * q + 1) * 128 + lab] + EPS;
                u32 b0 = __float_as_uint(v0);
                u32 b1 = __float_as_uint(v1);
                b0 = (b0 + 0x7FFFu + ((b0 >> 16) & 1u)) >> 16;          // RNE, low half
                b1 = (b1 + 0x7FFFu + ((b1 >> 16) & 1u)) & 0xFFFF0000u;  // RNE, high half
                w[q] = b0 | b1;
            }
            G2[((size_t)b * NCHUNK + (t0 >> 3) + chunk) * GR + r] =
                make_uint4(w[0], w[1], w[2], w[3]);
        }
    }
}

// ---------------------------------------------------------------------------
// Phase 2: linear-domain f64 scan, one wave per b.
// ---------------------------------------------------------------------------
__device__ __forceinline__ double dpp64_shr1(double x) {
    // lane i <- lane i-1 ; lane 0 -> 0.0 (bound_ctrl=false keeps old=0)
    union { double d; u32 u[2]; } in, out;
    in.d = x;
    out.u[0] = (u32)__builtin_amdgcn_update_dpp(0, (int)in.u[0], 0x138, 0xF, 0xF, false);
    out.u[1] = (u32)__builtin_amdgcn_update_dpp(0, (int)in.u[1], 0x138, 0xF, 0xF, false);
    return out.d;
}
template <int CTRL>
__device__ __forceinline__ u32 dpp_maxu_step(u32 m) {
    u32 t = (u32)__builtin_amdgcn_update_dpp(0, (int)m, CTRL, 0xF, 0xF, false);
    return m > t ? m : t;
}
__device__ __forceinline__ double exp2_exact(int e) {  // 2^e, |e| < 900
    union { double d; u64 u; } s; s.u = (u64)(1023 + e) << 52; return s.d;
}

struct Bank { uint4 own[4]; uint4 blk[4]; };

__global__ __launch_bounds__(64, 1)
void scan_kernel(const int* __restrict__ y_true,
                 const uint4* __restrict__ G2,
                 float* __restrict__ out) {
    const int b = blockIdx.x;
    const int l = threadIdx.x;

    const int lab = y_true[b * L + l];
    const int lab_prev = __shfl_up(lab, 1);
    const bool allow1 = (l >= 1) && (lab != lab_prev);

    const uint4* __restrict__ ownB = G2 + (size_t)b * NCHUNK * GR + l;
    const uint4* __restrict__ blkB = G2 + (size_t)b * NCHUNK * GR + L;  // uniform

    auto load_bank = [&](Bank& bk, int c0) {
#pragma unroll
        for (int c = 0; c < 4; ++c) {
            bk.own[c] = ownB[(c0 + c) * GR];
            bk.blk[c] = blkB[(c0 + c) * GR];
        }
    };

    // Virtual pre-state: step t=0 of the uniform body produces the true init.
    double d0 = (l == 0) ? 1.0 : 0.0;   // alpha[2l]
    double d1 = 0.0;                    // alpha[2l+1]
    double d2 = 0.0;                    // alpha[128] (real on lane 63)
    int Ce = 0;                         // log2 scale: alpha_true = d * 2^Ce

    auto consume_bank = [&](const Bank& bk) {
#pragma unroll
        for (int c = 0; c < 4; ++c) {
            const u32* ow = (const u32*)&bk.own[c];
            const u32* bw = (const u32*)&bk.blk[c];
#pragma unroll
            for (int j = 0; j < 8; ++j) {
                const u32 wo = ow[j >> 1], wb = bw[j >> 1];
                const float fl = __uint_as_float((j & 1) ? (wo & 0xFFFF0000u) : (wo << 16));
                const float fb = __uint_as_float((j & 1) ? (wb & 0xFFFF0000u) : (wb << 16));
                const double Pl = (double)fl, Pb = (double)fb;
                const double p0  = dpp64_shr1(d1);          // alpha[2l-1]
                const double sel = allow1 ? p0 : 0.0;
                const double nd0 = (d0 + p0) * Pb;
                const double nd2 = (d2 + d1) * Pb;
                const double nd1 = (d1 + (d0 + sel)) * Pl;
                d0 = nd0; d1 = nd1; d2 = nd2;
            }
        }
    };

    auto renorm = [&]() {
        // Wave-max of state magnitudes via integer max on the f64 hi-word
        // (positive doubles order like their bit patterns). Exact 2^-e scale.
        u32 h0 = (u32)__double2hiint(d0);
        u32 h1 = (u32)__double2hiint(d1);
        u32 m = h0 > h1 ? h0 : h1;
        m = dpp_maxu_step<0x111>(m);     // row_shr:1
        m = dpp_maxu_step<0x112>(m);     // row_shr:2
        m = dpp_maxu_step<0x114>(m);     // row_shr:4
        m = dpp_maxu_step<0x118>(m);     // row_shr:8
        m = dpp_maxu_step<0x142>(m);     // row_bcast:15
        m = dpp_maxu_step<0x143>(m);     // row_bcast:31 -> lane 63 has wave max
        const u32 M = (u32)__builtin_amdgcn_readlane((int)m, 63);
        const int e = (int)((M >> 20) & 0x7FFu) - 1023;
        const double s = exp2_exact(-e);
        d0 *= s; d1 *= s; d2 *= s;
        Ce += e;
    };

    Bank A, Bk;
    load_bank(A, 0);
    load_bank(Bk, 4);

#pragma unroll 1
    for (int k = 0; k < 16; k += 2) {    // 16 banks x 32 steps = 512 steps
        consume_bank(A);
        if (k + 2 < 16) load_bank(A, (k + 2) * 4);
        renorm();
        consume_bank(Bk);
        if (k + 3 < 16) load_bank(Bk, (k + 3) * 4);
        renorm();
    }

    if (l == 63) {
        // loss = -log(alpha[128] + alpha[127]); states scaled by 2^Ce.
        const double sum = d1 + d2;                   // > 0, normal (renormed)
        const int ee = ((__double2hiint(sum) >> 20) & 0x7FF) - 1023;
        const float mant = (float)(sum * exp2_exact(-ee));   // in [1,2)
        out[b] = -((float)(Ce + ee) + __log2f(mant)) * LN2;
    }
}

// ---------------------------------------------------------------------------
// Fallback (known-correct) if workspace is too small for G2.
// ---------------------------------------------------------------------------
__device__ __forceinline__ float lae2(float x, float y) {
    float m = fmaxf(x, y);
    float d = fminf(x, y) - m;
    return m + __logf(1.0f + __expf(d));
}
__device__ __forceinline__ float lae3(float x, float y, float z) {
    float m = fmaxf(fmaxf(x, y), z);
    float e = __expf(x - m) + __expf(y - m) + __expf(z - m);
    return m + __logf(e);
}
__global__ __launch_bounds__(64)
void ctc_fallback(const int* __restrict__ y_true,
                  const float* __restrict__ y_pred,
                  float* __restrict__ out) {
    const int b = blockIdx.x;
    const int l = threadIdx.x;
    const float* __restrict__ pb = y_pred + (size_t)b * T * C;
    const int lab = y_true[b * L + l];
    const int lab_prev = __shfl_up(lab, 1);
    const bool allow1 = (l >= 1) && (lab != lab_prev);
    float a0, a1, a2;
    {
        float pbl = pb[BLANK];
        float pla = pb[lab];
        a0 = (l == 0) ? __logf(pbl + EPS) : NEG;
        a1 = (l == 0) ? __logf(pla + EPS) : NEG;
        a2 = NEG;
    }
    for (int t = 1; t < T; ++t) {
        const float lpb = __logf(pb[t * C + BLANK] + EPS);
        const float lpl = __logf(pb[t * C + lab] + EPS);
        float p0 = __shfl_up(a1, 1);
        if (l == 0) p0 = NEG;
        const float na0 = lae2(a0, p0) + lpb;
        const float na1 = lae3(a1, a0, allow1 ? p0 : NEG) + lpl;
        const float na2 = lae2(a2, a1) + lpb;
        a0 = na0; a1 = na1; a2 = na2;
    }
    if (l == 63) out[b] = -lae2(a2, a1);
}

extern "C" void kernel_launch(void* const* d_in, const int* in_sizes, int n_in,
                              void* d_out, int out_size, void* d_ws, size_t ws_size,
                              hipStream_t stream) {
    const int*   y_true = (const int*)d_in[0];
    const float* y_pred = (const float*)d_in[1];
    float*       out    = (float*)d_out;

    const size_t need = (size_t)B * NCHUNK * GR * sizeof(uint4);  // ~34 MB
    if (ws_size >= need) {
        uint4* G2 = (uint4*)d_ws;
        gather_kernel<<<dim3(B * (T / 64)), dim3(256), 0, stream>>>(y_true, y_pred, G2);
        scan_kernel<<<dim3(B), dim3(64), 0, stream>>>(y_true, G2, out);
    } else {
        ctc_fallback<<<dim3(B), dim3(64), 0, stream>>>(y_true, y_pred, out);
    }
}

// Round 6
// 213.033 us; speedup vs baseline: 1.6843x; 1.0042x over previous
//
#include <hip/hip_runtime.h>
#include <hip/hip_bf16.h>

// CTC loss, two-phase:
//   Phase 1 (gather, barrier-free): each wave loads full t-rows (float2/lane,
//     coalesced 512B), extracts p[t][lab_r] via ds_bpermute (lane crossbar, no
//     LDS staging, no __syncthreads, no bank conflicts), packs 8 timesteps to
//     bf16 uint4. G2a[b][chunk][r<64] label rows; G2b[b][chunk] blank row.
//   Phase 2 (scan): one wave per b, alpha recursion in LINEAR f64 domain,
//     DPP wave_shr neighbor term, exact power-of-2 renorm every 32 steps via
//     integer exponent max-reduce. Ping-pong register banks, compact loop.

typedef unsigned int u32;
typedef unsigned long long u64;

constexpr int B = 512, T = 512, C = 128, L = 64;
constexpr int BLANK = C - 1;     // 127
constexpr int NCHUNK = T / 8;    // 64 chunks of 8 timesteps
constexpr float EPS = 1e-7f;
constexpr float NEG = -1e30f;
constexpr float LN2 = 0.69314718055994530942f;

__device__ __forceinline__ u32 rne16(u32 b) {       // f32 bits -> bf16 (RNE)
    return (b + 0x7FFFu + ((b >> 16) & 1u)) >> 16;
}

// ---------------------------------------------------------------------------
// Phase 1: bpermute gather. Block = (b, half of chunks), 256 thr = 4 waves.
// Wave w handles 8 consecutive chunks; per chunk: 8 coalesced row loads,
// 16 bpermutes, bf16 pack, 1 coalesced 1KB store (+ lane0 blank store).
// ---------------------------------------------------------------------------
__global__ __launch_bounds__(256)
void gather_kernel(const int* __restrict__ y_true,
                   const float* __restrict__ y_pred,
                   uint4* __restrict__ G2a,     // [B][NCHUNK][64]
                   uint4* __restrict__ G2b) {   // [B][NCHUNK]
    const int b    = blockIdx.x >> 1;
    const int half = blockIdx.x & 1;
    const int wave = threadIdx.x >> 6;
    const int lane = threadIdx.x & 63;

    const int lab  = y_true[b * L + lane];       // label owned by this lane (r=lane)
    const int perm = (lab >> 1) << 2;            // bpermute byte address
    const bool sel_hi = (lab & 1);

    const float2* __restrict__ base =
        (const float2*)(y_pred + (size_t)b * T * C) + lane;   // lane's 2 classes
    const int c0 = half * 32 + wave * 8;          // 8 consecutive chunks per wave

    float2 buf[2][8];
#pragma unroll
    for (int j = 0; j < 8; ++j) buf[0][j] = base[(c0 * 8 + j) * 64];

#pragma unroll
    for (int i = 0; i < 8; ++i) {
        const int c = c0 + i;
        if (i + 1 < 8) {
#pragma unroll
            for (int j = 0; j < 8; ++j)
                buf[(i + 1) & 1][j] = base[((c + 1) * 8 + j) * 64];
        }
        const float2* row = buf[i & 1];

        u32 gl[8], gb[8];
#pragma unroll
        for (int j = 0; j < 8; ++j) {
            const int vx = __builtin_amdgcn_ds_bpermute(perm, __float_as_int(row[j].x));
            const int vy = __builtin_amdgcn_ds_bpermute(perm, __float_as_int(row[j].y));
            const float v = __int_as_float(sel_hi ? vy : vx) + EPS;
            gl[j] = __float_as_uint(v);
            gb[j] = __float_as_uint(__shfl(row[j].y, 63) + EPS);  // class 127
        }
        u32 wl[4], wb[4];
#pragma unroll
        for (int q = 0; q < 4; ++q) {
            wl[q] = rne16(gl[2 * q]) | (rne16(gl[2 * q + 1]) << 16);
            wb[q] = rne16(gb[2 * q]) | (rne16(gb[2 * q + 1]) << 16);
        }
        G2a[(((size_t)b * NCHUNK + c) << 6) + lane] = make_uint4(wl[0], wl[1], wl[2], wl[3]);
        if (lane == 0)
            G2b[(size_t)b * NCHUNK + c] = make_uint4(wb[0], wb[1], wb[2], wb[3]);
    }
}

// ---------------------------------------------------------------------------
// Phase 2: linear-domain f64 scan, one wave per b.  (R5 math, new G layout.)
// ---------------------------------------------------------------------------
__device__ __forceinline__ double dpp64_shr1(double x) {
    // lane i <- lane i-1 ; lane 0 -> 0.0
    union { double d; u32 u[2]; } in, out;
    in.d = x;
    out.u[0] = (u32)__builtin_amdgcn_update_dpp(0, (int)in.u[0], 0x138, 0xF, 0xF, false);
    out.u[1] = (u32)__builtin_amdgcn_update_dpp(0, (int)in.u[1], 0x138, 0xF, 0xF, false);
    return out.d;
}
template <int CTRL>
__device__ __forceinline__ u32 dpp_maxu_step(u32 m) {
    u32 t = (u32)__builtin_amdgcn_update_dpp(0, (int)m, CTRL, 0xF, 0xF, false);
    return m > t ? m : t;
}
__device__ __forceinline__ double exp2_exact(int e) {  // 2^e
    union { double d; u64 u; } s; s.u = (u64)(1023 + e) << 52; return s.d;
}

struct Bank { uint4 own[4]; uint4 blk[4]; };

__global__ __launch_bounds__(64, 1)
void scan_kernel(const int* __restrict__ y_true,
                 const uint4* __restrict__ G2a,
                 const uint4* __restrict__ G2b,
                 float* __restrict__ out) {
    const int b = blockIdx.x;
    const int l = threadIdx.x;

    const int lab = y_true[b * L + l];
    const int lab_prev = __shfl_up(lab, 1);
    const bool allow1 = (l >= 1) && (lab != lab_prev);

    const uint4* __restrict__ ownB = G2a + (((size_t)b * NCHUNK) << 6) + l;
    const uint4* __restrict__ blkB = G2b + (size_t)b * NCHUNK;

    auto load_bank = [&](Bank& bk, int c0) {
#pragma unroll
        for (int c = 0; c < 4; ++c) {
            bk.own[c] = ownB[(size_t)(c0 + c) << 6];
            bk.blk[c] = blkB[c0 + c];
        }
    };

    // Virtual pre-state: step t=0 of the uniform body produces the true init.
    double d0 = (l == 0) ? 1.0 : 0.0;   // alpha[2l]
    double d1 = 0.0;                    // alpha[2l+1]
    double d2 = 0.0;                    // alpha[128] (real on lane 63)
    int Ce = 0;                         // log2 scale: alpha_true = d * 2^Ce

    auto consume_bank = [&](const Bank& bk) {
#pragma unroll
        for (int c = 0; c < 4; ++c) {
            const u32* ow = (const u32*)&bk.own[c];
            const u32* bw = (const u32*)&bk.blk[c];
#pragma unroll
            for (int j = 0; j < 8; ++j) {
                const u32 wo = ow[j >> 1], wb = bw[j >> 1];
                const float fl = __uint_as_float((j & 1) ? (wo & 0xFFFF0000u) : (wo << 16));
                const float fb = __uint_as_float((j & 1) ? (wb & 0xFFFF0000u) : (wb << 16));
                const double Pl = (double)fl, Pb = (double)fb;
                const double p0  = dpp64_shr1(d1);          // alpha[2l-1]
                const double sel = allow1 ? p0 : 0.0;
                const double nd0 = (d0 + p0) * Pb;
                const double nd2 = (d2 + d1) * Pb;
                const double nd1 = (d1 + (d0 + sel)) * Pl;
                d0 = nd0; d1 = nd1; d2 = nd2;
            }
        }
    };

    auto renorm = [&]() {
        u32 h0 = (u32)__double2hiint(d0);
        u32 h1 = (u32)__double2hiint(d1);
        u32 m = h0 > h1 ? h0 : h1;
        m = dpp_maxu_step<0x111>(m);     // row_shr:1
        m = dpp_maxu_step<0x112>(m);     // row_shr:2
        m = dpp_maxu_step<0x114>(m);     // row_shr:4
        m = dpp_maxu_step<0x118>(m);     // row_shr:8
        m = dpp_maxu_step<0x142>(m);     // row_bcast:15
        m = dpp_maxu_step<0x143>(m);     // row_bcast:31 -> lane 63 has wave max
        const u32 M = (u32)__builtin_amdgcn_readlane((int)m, 63);
        const int e = (int)((M >> 20) & 0x7FFu) - 1023;
        const double s = exp2_exact(-e);
        d0 *= s; d1 *= s; d2 *= s;
        Ce += e;
    };

    Bank A, Bk;
    load_bank(A, 0);
    load_bank(Bk, 4);

#pragma unroll 1
    for (int k = 0; k < 16; k += 2) {    // 16 banks x 32 steps = 512 steps
        consume_bank(A);
        if (k + 2 < 16) load_bank(A, (k + 2) * 4);
        renorm();
        consume_bank(Bk);
        if (k + 3 < 16) load_bank(Bk, (k + 3) * 4);
        renorm();
    }

    if (l == 63) {
        const double sum = d1 + d2;                   // alpha[127]+alpha[128]
        const int ee = ((__double2hiint(sum) >> 20) & 0x7FF) - 1023;
        const float mant = (float)(sum * exp2_exact(-ee));   // in [1,2)
        out[b] = -((float)(Ce + ee) + __log2f(mant)) * LN2;
    }
}

// ---------------------------------------------------------------------------
// Fallback (known-correct) if workspace is too small.
// ---------------------------------------------------------------------------
__device__ __forceinline__ float lae2(float x, float y) {
    float m = fmaxf(x, y);
    float d = fminf(x, y) - m;
    return m + __logf(1.0f + __expf(d));
}
__device__ __forceinline__ float lae3(float x, float y, float z) {
    float m = fmaxf(fmaxf(x, y), z);
    float e = __expf(x - m) + __expf(y - m) + __expf(z - m);
    return m + __logf(e);
}
__global__ __launch_bounds__(64)
void ctc_fallback(const int* __restrict__ y_true,
                  const float* __restrict__ y_pred,
                  float* __restrict__ out) {
    const int b = blockIdx.x;
    const int l = threadIdx.x;
    const float* __restrict__ pb = y_pred + (size_t)b * T * C;
    const int lab = y_true[b * L + l];
    const int lab_prev = __shfl_up(lab, 1);
    const bool allow1 = (l >= 1) && (lab != lab_prev);
    float a0, a1, a2;
    {
        float pbl = pb[BLANK];
        float pla = pb[lab];
        a0 = (l == 0) ? __logf(pbl + EPS) : NEG;
        a1 = (l == 0) ? __logf(pla + EPS) : NEG;
        a2 = NEG;
    }
    for (int t = 1; t < T; ++t) {
        const float lpb = __logf(pb[t * C + BLANK] + EPS);
        const float lpl = __logf(pb[t * C + lab] + EPS);
        float p0 = __shfl_up(a1, 1);
        if (l == 0) p0 = NEG;
        const float na0 = lae2(a0, p0) + lpb;
        const float na1 = lae3(a1, a0, allow1 ? p0 : NEG) + lpl;
        const float na2 = lae2(a2, a1) + lpb;
        a0 = na0; a1 = na1; a2 = na2;
    }
    if (l == 63) out[b] = -lae2(a2, a1);
}

extern "C" void kernel_launch(void* const* d_in, const int* in_sizes, int n_in,
                              void* d_out, int out_size, void* d_ws, size_t ws_size,
                              hipStream_t stream) {
    const int*   y_true = (const int*)d_in[0];
    const float* y_pred = (const float*)d_in[1];
    float*       out    = (float*)d_out;

    const size_t nA = (size_t)B * NCHUNK * 64;              // label uint4s
    const size_t nB = (size_t)B * NCHUNK;                   // blank uint4s
    const size_t need = (nA + nB) * sizeof(uint4);          // ~34 MB
    if (ws_size >= need) {
        uint4* G2a = (uint4*)d_ws;
        uint4* G2b = G2a + nA;
        gather_kernel<<<dim3(B * 2), dim3(256), 0, stream>>>(y_true, y_pred, G2a, G2b);
        scan_kernel<<<dim3(B), dim3(64), 0, stream>>>(y_true, G2a, G2b, out);
    } else {
        ctc_fallback<<<dim3(B), dim3(64), 0, stream>>>(y_true, y_pred, out);
    }
}